// Round 19
// baseline (292.734 us; speedup 1.0000x reference)
//
#include <hip/hip_runtime.h>
#include <hip/hip_bf16.h>

#define HEADS 3
#define HID 64
#define OUTW (HEADS * HID)   // 192
#define NS 128               // node feature size
#define NB_LSUM 2048         // k_lsum grid (partials buffer sized to match)

typedef __attribute__((ext_vector_type(8))) short bf16x8;
typedef __attribute__((ext_vector_type(4))) float f32x4;

__device__ __forceinline__ float lrelu(float x) {
    return x > 0.f ? x : 0.2f * x;
}

__device__ __forceinline__ unsigned short f2bf(float f) {
    unsigned u = __float_as_uint(f);
    u += 0x7fff + ((u >> 16) & 1);   // RNE
    return (unsigned short)(u >> 16);
}

__device__ __forceinline__ float bf2f(unsigned short u) {
    return __uint_as_float((unsigned)u << 16);
}

// ---------------- CSR build (by dst) ----------------

__global__ void k_zero_int(int* p, int n) {
    int i = blockIdx.x * blockDim.x + threadIdx.x;
    for (; i < n; i += gridDim.x * blockDim.x) p[i] = 0;
}

__global__ void k_hist(const int* __restrict__ key, int* __restrict__ cnt, int E) {
    int i = blockIdx.x * blockDim.x + threadIdx.x;
    for (; i < E; i += gridDim.x * blockDim.x) atomicAdd(&cnt[key[i]], 1);
}

__global__ void k_scan1(const int* __restrict__ cnt, int* __restrict__ rowstart,
                        int* __restrict__ blocksums, int N) {
    int t = threadIdx.x;
    int base = blockIdx.x * 1024 + t * 4;
    int v[4];
    int ts = 0;
#pragma unroll
    for (int j = 0; j < 4; ++j) {
        v[j] = (base + j < N) ? cnt[base + j] : 0;
        ts += v[j];
    }
    __shared__ int sh[256];
    sh[t] = ts;
    __syncthreads();
    for (int off = 1; off < 256; off <<= 1) {
        int x = 0;
        if (t >= off) x = sh[t - off];
        __syncthreads();
        if (t >= off) sh[t] += x;
        __syncthreads();
    }
    int excl = sh[t] - ts;
    if (t == 255) blocksums[blockIdx.x] = sh[255];
    int run = excl;
#pragma unroll
    for (int j = 0; j < 4; ++j) {
        if (base + j < N) rowstart[base + j] = run;
        run += v[j];
    }
}

__global__ void k_scan2(int* blocksums, int nb) {
    if (blockIdx.x == 0 && threadIdx.x == 0) {
        int s = 0;
        for (int i = 0; i < nb; ++i) {
            int v = blocksums[i];
            blocksums[i] = s;
            s += v;
        }
    }
}

__global__ void k_scan3(int* __restrict__ rowstart, const int* __restrict__ blocksums,
                        int* __restrict__ cursor, int N, int E) {
    int i = blockIdx.x * blockDim.x + threadIdx.x;
    if (i < N) {
        int v = rowstart[i] + blocksums[i >> 10];
        rowstart[i] = v;
        cursor[i] = v;
    }
    if (i == 0) rowstart[N] = E;
}

__global__ void k_scatter(const int* __restrict__ src, const int* __restrict__ dst,
                          int* __restrict__ cursor, int2* __restrict__ csr_sd, int E) {
    int i = blockIdx.x * blockDim.x + threadIdx.x;
    for (; i < E; i += gridDim.x * blockDim.x) {
        int d = dst[i];
        int p = atomicAdd(&cursor[d], 1);
        csr_sd[p] = make_int2(src[i], d);
    }
}

// ---------------- prep: wl1/wr1[k,h] = sum_f W1[k, h*64+f] * al1/ar1[h,f] ------

__global__ void k_prep(const float* __restrict__ W1, const float* __restrict__ al1,
                       const float* __restrict__ ar1, float* __restrict__ wlr1) {
    int t = threadIdx.x;
    if (t >= 192) return;
    int k = t & 63, hh = t >> 6;
    float sl = 0.f, sr = 0.f;
#pragma unroll 8
    for (int f = 0; f < 64; ++f) {
        float w = W1[k * OUTW + hh * 64 + f];
        sl = fmaf(w, al1[hh * 64 + f], sl);
        sr = fmaf(w, ar1[hh * 64 + f], sr);
    }
    wlr1[k * 8 + hh] = sl;
    wlr1[k * 8 + 4 + hh] = sr;
}

// ---------------- prepW: Wtb[col][k] = bf16(W0[k][col]) (one-time transpose) ----

__global__ void k_prepW(const float* __restrict__ W, unsigned short* __restrict__ Wtb) {
    int t = blockIdx.x * blockDim.x + threadIdx.x;   // 0..1535
    int c = t >> 3, k0 = (t & 7) * 16;
    if (c >= OUTW) return;
    for (int k = k0; k < k0 + 16; ++k)
        Wtb[(size_t)c * NS + k] = f2bf(W[(size_t)k * OUTW + c]);
}

// ---------------- edge weights: w4[i] = exp(lrelu(el[src_i] + er[dst_i])) ------

__global__ __launch_bounds__(256) void k_w(const float* __restrict__ elr,
                                           const int2* __restrict__ csr_sd,
                                           float4* __restrict__ w4, int E) {
    int i = blockIdx.x * blockDim.x + threadIdx.x;
    for (; i < E; i += gridDim.x * blockDim.x) {
        int2 sd = csr_sd[i];
        float4 el = *(const float4*)(elr + (size_t)sd.x * 8);
        float4 er = *(const float4*)(elr + (size_t)sd.y * 8 + 4);
        float4 o;
        o.x = __expf(lrelu(el.x + er.x));
        o.y = __expf(lrelu(el.y + er.y));
        o.z = __expf(lrelu(el.z + er.z));
        o.w = 0.f;
        w4[i] = o;
    }
}

// ---------------- GEMM0 via MFMA bf16: Z16[M,192] = X[M,128] @ W0 --------------

#define LDK 136

__global__ __launch_bounds__(256) void k_gemm5(const float* __restrict__ X,
                                               const unsigned short* __restrict__ Wtb,
                                               const float* __restrict__ al,
                                               const float* __restrict__ ar,
                                               unsigned short* __restrict__ Z16,
                                               float* __restrict__ elr, int M) {
    __shared__ __align__(16) unsigned short Xs[64][LDK];
    __shared__ __align__(16) unsigned short Ws[192][LDK];
    __shared__ float elp[4][64][8];
    const int tid = threadIdx.x;
    const int lane = tid & 63;
    const int w = tid >> 6;
    const int r0 = blockIdx.x * 64;

    // stage W (bf16, transposed): 12 iters x 16B = full 192x128 bf16
    // (round-17/18 BUG: 6 iters with 16-elem chunk stride left HALF of Ws
    //  uninitialized -- uint4 is 8 bf16, so chunk stride must be 8.)
#pragma unroll
    for (int i = 0; i < 12; ++i) {
        int id = i * 256 + tid;          // 0..3071
        int col = id >> 4, ck = id & 15; // 16 chunks x 8 elems per col
        *(uint4*)&Ws[col][ck * 8] = *(const uint4*)(Wtb + (size_t)col * NS + ck * 8);
    }
    // stage X tile -> bf16
#pragma unroll
    for (int i = 0; i < 8; ++i) {
        int id = i * 256 + tid;
        int row = id >> 5, f4 = id & 31;
        int gr = r0 + row;
        if (gr >= M) gr = M - 1;
        float4 v = *(const float4*)(X + (size_t)gr * NS + f4 * 4);
        ushort4 u;
        u.x = f2bf(v.x); u.y = f2bf(v.y); u.z = f2bf(v.z); u.w = f2bf(v.w);
        *(ushort4*)&Xs[row][f4 * 4] = u;
    }
    __syncthreads();

    const int mrow = lane & 15;
    const int kgrp = (lane >> 4) * 8;

    bf16x8 bf[3][4];
#pragma unroll
    for (int c = 0; c < 3; ++c)
#pragma unroll
        for (int kb = 0; kb < 4; ++kb)
            bf[c][kb] = *(const bf16x8*)&Ws[(c * 4 + w) * 16 + mrow][kb * 32 + kgrp];

    f32x4 acc[4][3];
#pragma unroll
    for (int rb = 0; rb < 4; ++rb)
#pragma unroll
        for (int c = 0; c < 3; ++c) acc[rb][c] = (f32x4){0.f, 0.f, 0.f, 0.f};

#pragma unroll
    for (int rb = 0; rb < 4; ++rb) {
        bf16x8 af[4];
#pragma unroll
        for (int kb = 0; kb < 4; ++kb)
            af[kb] = *(const bf16x8*)&Xs[rb * 16 + mrow][kb * 32 + kgrp];
#pragma unroll
        for (int c = 0; c < 3; ++c)
#pragma unroll
            for (int kb = 0; kb < 4; ++kb)
                acc[rb][c] = __builtin_amdgcn_mfma_f32_16x16x32_bf16(
                    af[kb], bf[c][kb], acc[rb][c], 0, 0, 0);
    }

    float alv[3], arv[3];
#pragma unroll
    for (int c = 0; c < 3; ++c) {
        alv[c] = al[c * 64 + w * 16 + mrow];
        arv[c] = ar[c * 64 + w * 16 + mrow];
    }
#pragma unroll
    for (int rb = 0; rb < 4; ++rb) {
#pragma unroll
        for (int reg = 0; reg < 4; ++reg) {
            int row = r0 + rb * 16 + (lane >> 4) * 4 + reg;
            bool live = row < M;
            float pl[3], pr[3];
#pragma unroll
            for (int c = 0; c < 3; ++c) {
                float v = acc[rb][c][reg];
                if (live) Z16[(size_t)row * OUTW + (c * 4 + w) * 16 + mrow] = f2bf(v);
                pl[c] = v * alv[c];
                pr[c] = v * arv[c];
            }
#pragma unroll
            for (int m = 1; m < 16; m <<= 1) {
#pragma unroll
                for (int c = 0; c < 3; ++c) {
                    pl[c] += __shfl_xor(pl[c], m, 64);
                    pr[c] += __shfl_xor(pr[c], m, 64);
                }
            }
            if (mrow == 0) {
                int lrow = rb * 16 + (lane >> 4) * 4 + reg;
#pragma unroll
                for (int c = 0; c < 3; ++c) {
                    elp[w][lrow][c] = pl[c];
                    elp[w][lrow][4 + c] = pr[c];
                }
            }
        }
    }
    __syncthreads();
    if (tid < 64) {
        int row = r0 + tid;
        if (row < M) {
#pragma unroll
            for (int c = 0; c < 3; ++c) {
                float el = elp[0][tid][c] + elp[1][tid][c] + elp[2][tid][c] + elp[3][tid][c];
                float er = elp[0][tid][4 + c] + elp[1][tid][4 + c] + elp[2][tid][4 + c] +
                           elp[3][tid][4 + c];
                elr[(size_t)row * 8 + c] = el;
                elr[(size_t)row * 8 + 4 + c] = er;
            }
        }
    }
}

// ---------------- layer-0 aggregate; emits h1 (bf16) + el1/er1 (fp32) ----------

__global__ __launch_bounds__(256) void k_agg0(const unsigned short* __restrict__ z16,
                                              const float4* __restrict__ w4,
                                              const int* __restrict__ rowstart,
                                              const int2* __restrict__ csr_sd,
                                              const float* __restrict__ bias,
                                              const float* __restrict__ wlr1,
                                              unsigned short* __restrict__ h1b,
                                              float* __restrict__ elr1, int N) {
    int node = __builtin_amdgcn_readfirstlane(blockIdx.x * 4 + (threadIdx.x >> 6));
    int lane = threadIdx.x & 63;
    if (node >= N) return;
    float4 wl4 = *(const float4*)(wlr1 + lane * 8);
    float4 wr4 = *(const float4*)(wlr1 + lane * 8 + 4);
    int s = rowstart[node], e = rowstart[node + 1];
    float s0 = 0.f, s1 = 0.f, s2 = 0.f;
    float a0 = 0.f, a1 = 0.f, a2 = 0.f;
    int i = s;
    for (; i + 4 <= e; i += 4) {
        float4 w0 = w4[i];
        float4 w1 = w4[i + 1];
        float4 w2 = w4[i + 2];
        float4 w3 = w4[i + 3];
        int sr0 = csr_sd[i].x;
        int sr1 = csr_sd[i + 1].x;
        int sr2 = csr_sd[i + 2].x;
        int sr3 = csr_sd[i + 3].x;
        const unsigned short* zr0 = z16 + (size_t)sr0 * OUTW;
        const unsigned short* zr1 = z16 + (size_t)sr1 * OUTW;
        const unsigned short* zr2 = z16 + (size_t)sr2 * OUTW;
        const unsigned short* zr3 = z16 + (size_t)sr3 * OUTW;
        unsigned short p00 = zr0[lane], p01 = zr0[HID + lane], p02 = zr0[2 * HID + lane];
        unsigned short p10 = zr1[lane], p11 = zr1[HID + lane], p12 = zr1[2 * HID + lane];
        unsigned short p20 = zr2[lane], p21 = zr2[HID + lane], p22 = zr2[2 * HID + lane];
        unsigned short p30 = zr3[lane], p31 = zr3[HID + lane], p32 = zr3[2 * HID + lane];
        s0 += (w0.x + w1.x) + (w2.x + w3.x);
        s1 += (w0.y + w1.y) + (w2.y + w3.y);
        s2 += (w0.z + w1.z) + (w2.z + w3.z);
        a0 = fmaf(w0.x, bf2f(p00), a0);
        a1 = fmaf(w0.y, bf2f(p01), a1);
        a2 = fmaf(w0.z, bf2f(p02), a2);
        a0 = fmaf(w1.x, bf2f(p10), a0);
        a1 = fmaf(w1.y, bf2f(p11), a1);
        a2 = fmaf(w1.z, bf2f(p12), a2);
        a0 = fmaf(w2.x, bf2f(p20), a0);
        a1 = fmaf(w2.y, bf2f(p21), a1);
        a2 = fmaf(w2.z, bf2f(p22), a2);
        a0 = fmaf(w3.x, bf2f(p30), a0);
        a1 = fmaf(w3.y, bf2f(p31), a1);
        a2 = fmaf(w3.z, bf2f(p32), a2);
    }
    for (; i < e; ++i) {
        float4 wv = w4[i];
        int sr = csr_sd[i].x;
        const unsigned short* zr = z16 + (size_t)sr * OUTW;
        s0 += wv.x; s1 += wv.y; s2 += wv.z;
        a0 = fmaf(wv.x, bf2f(zr[lane]), a0);
        a1 = fmaf(wv.y, bf2f(zr[HID + lane]), a1);
        a2 = fmaf(wv.z, bf2f(zr[2 * HID + lane]), a2);
    }
    float r = bias[lane] + bias[HID + lane] + bias[2 * HID + lane];
    if (s0 > 0.f) r += a0 / s0;
    if (s1 > 0.f) r += a1 / s1;
    if (s2 > 0.f) r += a2 / s2;
    r *= (1.f / 3.f);

    h1b[(size_t)node * HID + lane] = f2bf(r);
    float pl0 = r * wl4.x, pl1 = r * wl4.y, pl2 = r * wl4.z;
    float pr0 = r * wr4.x, pr1 = r * wr4.y, pr2 = r * wr4.z;
#pragma unroll
    for (int m = 1; m < 64; m <<= 1) {
        pl0 += __shfl_xor(pl0, m, 64);
        pl1 += __shfl_xor(pl1, m, 64);
        pl2 += __shfl_xor(pl2, m, 64);
        pr0 += __shfl_xor(pr0, m, 64);
        pr1 += __shfl_xor(pr1, m, 64);
        pr2 += __shfl_xor(pr2, m, 64);
    }
    if (lane == 0) {
        elr1[(size_t)node * 8 + 0] = pl0;
        elr1[(size_t)node * 8 + 1] = pl1;
        elr1[(size_t)node * 8 + 2] = pl2;
        elr1[(size_t)node * 8 + 4] = pr0;
        elr1[(size_t)node * 8 + 5] = pr1;
        elr1[(size_t)node * 8 + 6] = pr2;
    }
}

// ---------------- layer-1: dst-grouped grid-stride pass (weights precomputed) --

__global__ __launch_bounds__(256) void k_lsum(const unsigned short* __restrict__ h1b,
                                              const float4* __restrict__ w4,
                                              const int* __restrict__ rowstart,
                                              const int2* __restrict__ csr_sd,
                                              float* __restrict__ partial, int N) {
    int lane = threadIdx.x & 63;
    int w = threadIdx.x >> 6;
    int wid = __builtin_amdgcn_readfirstlane(blockIdx.x * 4 + (threadIdx.x >> 6));
    int nw = gridDim.x * 4;
    float g0 = 0.f, g1 = 0.f, g2 = 0.f;
    for (int node = wid; node < N; node += nw) {
        int s = rowstart[node], e = rowstart[node + 1];
        if (s == e) continue;
        float s0 = 0.f, s1 = 0.f, s2 = 0.f;
        float a0 = 0.f, a1 = 0.f, a2 = 0.f;
        int i = s;
        for (; i + 4 <= e; i += 4) {
            float4 w0 = w4[i];
            float4 w1 = w4[i + 1];
            float4 w2 = w4[i + 2];
            float4 w3 = w4[i + 3];
            int sr0 = csr_sd[i].x;
            int sr1 = csr_sd[i + 1].x;
            int sr2 = csr_sd[i + 2].x;
            int sr3 = csr_sd[i + 3].x;
            float v0 = bf2f(h1b[(size_t)sr0 * HID + lane]);
            float v1 = bf2f(h1b[(size_t)sr1 * HID + lane]);
            float v2 = bf2f(h1b[(size_t)sr2 * HID + lane]);
            float v3 = bf2f(h1b[(size_t)sr3 * HID + lane]);
            s0 += (w0.x + w1.x) + (w2.x + w3.x);
            s1 += (w0.y + w1.y) + (w2.y + w3.y);
            s2 += (w0.z + w1.z) + (w2.z + w3.z);
            a0 = fmaf(w0.x, v0, a0);
            a1 = fmaf(w0.y, v0, a1);
            a2 = fmaf(w0.z, v0, a2);
            a0 = fmaf(w1.x, v1, a0);
            a1 = fmaf(w1.y, v1, a1);
            a2 = fmaf(w1.z, v1, a2);
            a0 = fmaf(w2.x, v2, a0);
            a1 = fmaf(w2.y, v2, a1);
            a2 = fmaf(w2.z, v2, a2);
            a0 = fmaf(w3.x, v3, a0);
            a1 = fmaf(w3.y, v3, a1);
            a2 = fmaf(w3.z, v3, a2);
        }
        for (; i < e; ++i) {
            float4 wv = w4[i];
            int sr = csr_sd[i].x;
            float v = bf2f(h1b[(size_t)sr * HID + lane]);
            s0 += wv.x; s1 += wv.y; s2 += wv.z;
            a0 = fmaf(wv.x, v, a0);
            a1 = fmaf(wv.y, v, a1);
            a2 = fmaf(wv.z, v, a2);
        }
        if (s0 > 0.f) g0 += a0 / s0;
        if (s1 > 0.f) g1 += a1 / s1;
        if (s2 > 0.f) g2 += a2 / s2;
    }
    __shared__ float sh[4][3][64];
    sh[w][0][lane] = g0;
    sh[w][1][lane] = g1;
    sh[w][2][lane] = g2;
    __syncthreads();
    if (w == 0) {
        float t0 = sh[0][0][lane] + sh[1][0][lane] + sh[2][0][lane] + sh[3][0][lane];
        float t1 = sh[0][1][lane] + sh[1][1][lane] + sh[2][1][lane] + sh[3][1][lane];
        float t2 = sh[0][2][lane] + sh[1][2][lane] + sh[2][2][lane] + sh[3][2][lane];
        float* p = partial + (size_t)blockIdx.x * OUTW;
        p[0 * HID + lane] = t0;
        p[1 * HID + lane] = t1;
        p[2 * HID + lane] = t2;
    }
}

// ---------------- reduce partials: macc[f] = sum_b partial[b][f] ---------------

__global__ __launch_bounds__(256) void k_red(const float* __restrict__ partial,
                                             float* __restrict__ macc, int nb) {
    int f = blockIdx.x;
    int t = threadIdx.x;
    float s = 0.f;
    for (int b = t; b < nb; b += 256) s += partial[(size_t)b * OUTW + f];
    __shared__ float sh[256];
    sh[t] = s;
    __syncthreads();
    for (int off = 128; off > 0; off >>= 1) {
        if (t < off) sh[t] += sh[t + off];
        __syncthreads();
    }
    if (t == 0) macc[f] = sh[0];
}

// ---------------- final: out[f] = macc @ W1_stacked /(3N) + mean bias ----------

__global__ void k_final(const float* __restrict__ macc, const float* __restrict__ W1,
                        const float* __restrict__ b1, float* __restrict__ out, int N) {
    int f = threadIdx.x;
    if (f >= HID) return;
    float s = 0.f;
#pragma unroll
    for (int hh = 0; hh < HEADS; ++hh)
        for (int k = 0; k < HID; ++k)
            s = fmaf(macc[hh * HID + k], W1[k * OUTW + hh * HID + f], s);
    float bb = b1[f] + b1[HID + f] + b1[2 * HID + f];
    out[f] = s / (3.0f * (float)N) + bb * (1.f / 3.f);
}

// ---------------- launch ----------------

extern "C" void kernel_launch(void* const* d_in, const int* in_sizes, int n_in,
                              void* d_out, int out_size, void* d_ws, size_t ws_size,
                              hipStream_t stream) {
    const float* h   = (const float*)d_in[0];
    const int* src   = (const int*)d_in[1];
    const int* dst   = (const int*)d_in[2];
    const float* W0  = (const float*)d_in[3];
    const float* al0 = (const float*)d_in[4];
    const float* ar0 = (const float*)d_in[5];
    const float* b0  = (const float*)d_in[6];
    const float* W1  = (const float*)d_in[7];
    const float* al1 = (const float*)d_in[8];
    const float* ar1 = (const float*)d_in[9];
    const float* b1  = (const float*)d_in[10];
    float* out = (float*)d_out;

    const int N = in_sizes[0] / NS;
    const int E = in_sizes[1];

    char* ws = (char*)d_ws;
    size_t off = 0;
    auto alloc = [&](size_t bytes) {
        size_t r = off;
        off = (off + bytes + 255) & ~(size_t)255;
        return r;
    };
    unsigned short* z16 = (unsigned short*)(ws + alloc((size_t)N * OUTW * 2));
    unsigned short* h1b = (unsigned short*)(ws + alloc((size_t)N * HID * 2));
    float* elr0     = (float*)(ws + alloc((size_t)N * 8 * 4));
    float* elr1     = (float*)(ws + alloc((size_t)N * 8 * 4));
    float4* w0arr   = (float4*)(ws + alloc((size_t)E * 16));
    float4* w1arr   = (float4*)(ws + alloc((size_t)E * 16));
    float* partial  = (float*)(ws + alloc((size_t)NB_LSUM * OUTW * 4));
    float* macc     = (float*)(ws + alloc(OUTW * 4));
    int* cnt        = (int*)(ws + alloc((size_t)N * 4));
    int* rowstart   = (int*)(ws + alloc((size_t)(N + 1) * 4));
    int* cursor     = (int*)(ws + alloc((size_t)N * 4));
    int2* csr_sd    = (int2*)(ws + alloc((size_t)E * 8));
    int* blocksums  = (int*)(ws + alloc(4096));
    float* wlr1     = (float*)(ws + alloc(64 * 8 * 4));
    unsigned short* Wtb = (unsigned short*)(ws + alloc((size_t)OUTW * NS * 2));

    const int nbScan = (N + 1023) / 1024;

    // CSR build (by dst) + weight prep
    k_zero_int<<<256, 256, 0, stream>>>(cnt, N);
    k_hist<<<2048, 256, 0, stream>>>(dst, cnt, E);
    k_scan1<<<nbScan, 256, 0, stream>>>(cnt, rowstart, blocksums, N);
    k_scan2<<<1, 64, 0, stream>>>(blocksums, nbScan);
    k_scan3<<<(N + 255) / 256, 256, 0, stream>>>(rowstart, blocksums, cursor, N, E);
    k_scatter<<<2048, 256, 0, stream>>>(src, dst, cursor, csr_sd, E);
    k_prep<<<1, 192, 0, stream>>>(W1, al1, ar1, wlr1);
    k_prepW<<<6, 256, 0, stream>>>(W0, Wtb);

    // layer 0 (MFMA GEMM) -> edge weights -> aggregate
    k_gemm5<<<(N + 63) / 64, 256, 0, stream>>>(h, Wtb, al0, ar0, z16, elr0, N);
    k_w<<<1024, 256, 0, stream>>>(elr0, csr_sd, w0arr, E);
    k_agg0<<<(N + 3) / 4, 256, 0, stream>>>(z16, w0arr, rowstart, csr_sd, b0, wlr1,
                                            h1b, elr1, N);

    // layer 1 (collapsed): edge weights -> grid-stride pass -> reduce -> matvec
    k_w<<<1024, 256, 0, stream>>>(elr1, csr_sd, w1arr, E);
    k_lsum<<<NB_LSUM, 256, 0, stream>>>(h1b, w1arr, rowstart, csr_sd, partial, N);
    k_red<<<OUTW, 256, 0, stream>>>(partial, macc, NB_LSUM);
    k_final<<<1, 64, 0, stream>>>(macc, W1, b1, out, N);
}

// Round 20
// 286.840 us; speedup vs baseline: 1.0205x; 1.0205x over previous
//
#include <hip/hip_runtime.h>
#include <hip/hip_bf16.h>
#include <hip/hip_fp8.h>

#define HEADS 3
#define HID 64
#define OUTW (HEADS * HID)   // 192
#define NS 128               // node feature size
#define NB_LSUM 2048         // k_lsum grid (partials buffer sized to match)

typedef __attribute__((ext_vector_type(8))) short bf16x8;
typedef __attribute__((ext_vector_type(4))) float f32x4;

__device__ __forceinline__ float lrelu(float x) {
    return x > 0.f ? x : 0.2f * x;
}

__device__ __forceinline__ unsigned short f2bf(float f) {
    unsigned u = __float_as_uint(f);
    u += 0x7fff + ((u >> 16) & 1);   // RNE
    return (unsigned short)(u >> 16);
}

__device__ __forceinline__ float bf2f(unsigned short u) {
    return __uint_as_float((unsigned)u << 16);
}

__device__ __forceinline__ unsigned char f2q(float f) {   // fp8 e4m3 (OCP) encode
    return __hip_fp8_e4m3(f).__x;
}

__device__ __forceinline__ float q2f(unsigned char b) {   // fp8 e4m3 decode
    __hip_fp8_e4m3 t;
    t.__x = b;
    return (float)t;
}

// ---------------- CSR build (by dst) ----------------

__global__ void k_zero_int(int* p, int n) {
    int i = blockIdx.x * blockDim.x + threadIdx.x;
    for (; i < n; i += gridDim.x * blockDim.x) p[i] = 0;
}

__global__ void k_hist(const int* __restrict__ key, int* __restrict__ cnt, int E) {
    int i = blockIdx.x * blockDim.x + threadIdx.x;
    for (; i < E; i += gridDim.x * blockDim.x) atomicAdd(&cnt[key[i]], 1);
}

__global__ void k_scan1(const int* __restrict__ cnt, int* __restrict__ rowstart,
                        int* __restrict__ blocksums, int N) {
    int t = threadIdx.x;
    int base = blockIdx.x * 1024 + t * 4;
    int v[4];
    int ts = 0;
#pragma unroll
    for (int j = 0; j < 4; ++j) {
        v[j] = (base + j < N) ? cnt[base + j] : 0;
        ts += v[j];
    }
    __shared__ int sh[256];
    sh[t] = ts;
    __syncthreads();
    for (int off = 1; off < 256; off <<= 1) {
        int x = 0;
        if (t >= off) x = sh[t - off];
        __syncthreads();
        if (t >= off) sh[t] += x;
        __syncthreads();
    }
    int excl = sh[t] - ts;
    if (t == 255) blocksums[blockIdx.x] = sh[255];
    int run = excl;
#pragma unroll
    for (int j = 0; j < 4; ++j) {
        if (base + j < N) rowstart[base + j] = run;
        run += v[j];
    }
}

__global__ void k_scan2(int* blocksums, int nb) {
    if (blockIdx.x == 0 && threadIdx.x == 0) {
        int s = 0;
        for (int i = 0; i < nb; ++i) {
            int v = blocksums[i];
            blocksums[i] = s;
            s += v;
        }
    }
}

__global__ void k_scan3(int* __restrict__ rowstart, const int* __restrict__ blocksums,
                        int* __restrict__ cursor, int N, int E) {
    int i = blockIdx.x * blockDim.x + threadIdx.x;
    if (i < N) {
        int v = rowstart[i] + blocksums[i >> 10];
        rowstart[i] = v;
        cursor[i] = v;
    }
    if (i == 0) rowstart[N] = E;
}

__global__ void k_scatter(const int* __restrict__ src, const int* __restrict__ dst,
                          int* __restrict__ cursor, int2* __restrict__ csr_sd, int E) {
    int i = blockIdx.x * blockDim.x + threadIdx.x;
    for (; i < E; i += gridDim.x * blockDim.x) {
        int d = dst[i];
        int p = atomicAdd(&cursor[d], 1);
        csr_sd[p] = make_int2(src[i], d);
    }
}

// ---------------- prep: wl1/wr1[k,h] = sum_f W1[k, h*64+f] * al1/ar1[h,f] ------

__global__ void k_prep(const float* __restrict__ W1, const float* __restrict__ al1,
                       const float* __restrict__ ar1, float* __restrict__ wlr1) {
    int t = threadIdx.x;
    if (t >= 192) return;
    int k = t & 63, hh = t >> 6;
    float sl = 0.f, sr = 0.f;
#pragma unroll 8
    for (int f = 0; f < 64; ++f) {
        float w = W1[k * OUTW + hh * 64 + f];
        sl = fmaf(w, al1[hh * 64 + f], sl);
        sr = fmaf(w, ar1[hh * 64 + f], sr);
    }
    wlr1[k * 8 + hh] = sl;
    wlr1[k * 8 + 4 + hh] = sr;
}

// ---------------- prepW: Wtb[col][k] = bf16(W0[k][col]) (one-time transpose) ----

__global__ void k_prepW(const float* __restrict__ W, unsigned short* __restrict__ Wtb) {
    int t = blockIdx.x * blockDim.x + threadIdx.x;   // 0..1535
    int c = t >> 3, k0 = (t & 7) * 16;
    if (c >= OUTW) return;
    for (int k = k0; k < k0 + 16; ++k)
        Wtb[(size_t)c * NS + k] = f2bf(W[(size_t)k * OUTW + c]);
}

// ---------------- edge weights: w4[i] = exp(lrelu(el[src_i] + er[dst_i])) ------

__global__ __launch_bounds__(256) void k_w(const float* __restrict__ elr,
                                           const int2* __restrict__ csr_sd,
                                           float4* __restrict__ w4, int E) {
    int i = blockIdx.x * blockDim.x + threadIdx.x;
    for (; i < E; i += gridDim.x * blockDim.x) {
        int2 sd = csr_sd[i];
        float4 el = *(const float4*)(elr + (size_t)sd.x * 8);
        float4 er = *(const float4*)(elr + (size_t)sd.y * 8 + 4);
        float4 o;
        o.x = __expf(lrelu(el.x + er.x));
        o.y = __expf(lrelu(el.y + er.y));
        o.z = __expf(lrelu(el.z + er.z));
        o.w = 0.f;
        w4[i] = o;
    }
}

// ---------------- GEMM0 via MFMA bf16: Z16[M,192] = X[M,128] @ W0 --------------

#define LDK 136

__global__ __launch_bounds__(256) void k_gemm5(const float* __restrict__ X,
                                               const unsigned short* __restrict__ Wtb,
                                               const float* __restrict__ al,
                                               const float* __restrict__ ar,
                                               unsigned short* __restrict__ Z16,
                                               float* __restrict__ elr, int M) {
    __shared__ __align__(16) unsigned short Xs[64][LDK];
    __shared__ __align__(16) unsigned short Ws[192][LDK];
    __shared__ float elp[4][64][8];
    const int tid = threadIdx.x;
    const int lane = tid & 63;
    const int w = tid >> 6;
    const int r0 = blockIdx.x * 64;

    // stage W (bf16, transposed): 12 iters x 16B (uint4 = 8 bf16, chunk stride 8)
#pragma unroll
    for (int i = 0; i < 12; ++i) {
        int id = i * 256 + tid;          // 0..3071
        int col = id >> 4, ck = id & 15;
        *(uint4*)&Ws[col][ck * 8] = *(const uint4*)(Wtb + (size_t)col * NS + ck * 8);
    }
    // stage X tile -> bf16
#pragma unroll
    for (int i = 0; i < 8; ++i) {
        int id = i * 256 + tid;
        int row = id >> 5, f4 = id & 31;
        int gr = r0 + row;
        if (gr >= M) gr = M - 1;
        float4 v = *(const float4*)(X + (size_t)gr * NS + f4 * 4);
        ushort4 u;
        u.x = f2bf(v.x); u.y = f2bf(v.y); u.z = f2bf(v.z); u.w = f2bf(v.w);
        *(ushort4*)&Xs[row][f4 * 4] = u;
    }
    __syncthreads();

    const int mrow = lane & 15;
    const int kgrp = (lane >> 4) * 8;

    bf16x8 bf[3][4];
#pragma unroll
    for (int c = 0; c < 3; ++c)
#pragma unroll
        for (int kb = 0; kb < 4; ++kb)
            bf[c][kb] = *(const bf16x8*)&Ws[(c * 4 + w) * 16 + mrow][kb * 32 + kgrp];

    f32x4 acc[4][3];
#pragma unroll
    for (int rb = 0; rb < 4; ++rb)
#pragma unroll
        for (int c = 0; c < 3; ++c) acc[rb][c] = (f32x4){0.f, 0.f, 0.f, 0.f};

#pragma unroll
    for (int rb = 0; rb < 4; ++rb) {
        bf16x8 af[4];
#pragma unroll
        for (int kb = 0; kb < 4; ++kb)
            af[kb] = *(const bf16x8*)&Xs[rb * 16 + mrow][kb * 32 + kgrp];
#pragma unroll
        for (int c = 0; c < 3; ++c)
#pragma unroll
            for (int kb = 0; kb < 4; ++kb)
                acc[rb][c] = __builtin_amdgcn_mfma_f32_16x16x32_bf16(
                    af[kb], bf[c][kb], acc[rb][c], 0, 0, 0);
    }

    float alv[3], arv[3];
#pragma unroll
    for (int c = 0; c < 3; ++c) {
        alv[c] = al[c * 64 + w * 16 + mrow];
        arv[c] = ar[c * 64 + w * 16 + mrow];
    }
#pragma unroll
    for (int rb = 0; rb < 4; ++rb) {
#pragma unroll
        for (int reg = 0; reg < 4; ++reg) {
            int row = r0 + rb * 16 + (lane >> 4) * 4 + reg;
            bool live = row < M;
            float pl[3], pr[3];
#pragma unroll
            for (int c = 0; c < 3; ++c) {
                float v = acc[rb][c][reg];
                if (live) Z16[(size_t)row * OUTW + (c * 4 + w) * 16 + mrow] = f2bf(v);
                pl[c] = v * alv[c];
                pr[c] = v * arv[c];
            }
#pragma unroll
            for (int m = 1; m < 16; m <<= 1) {
#pragma unroll
                for (int c = 0; c < 3; ++c) {
                    pl[c] += __shfl_xor(pl[c], m, 64);
                    pr[c] += __shfl_xor(pr[c], m, 64);
                }
            }
            if (mrow == 0) {
                int lrow = rb * 16 + (lane >> 4) * 4 + reg;
#pragma unroll
                for (int c = 0; c < 3; ++c) {
                    elp[w][lrow][c] = pl[c];
                    elp[w][lrow][4 + c] = pr[c];
                }
            }
        }
    }
    __syncthreads();
    if (tid < 64) {
        int row = r0 + tid;
        if (row < M) {
#pragma unroll
            for (int c = 0; c < 3; ++c) {
                float el = elp[0][tid][c] + elp[1][tid][c] + elp[2][tid][c] + elp[3][tid][c];
                float er = elp[0][tid][4 + c] + elp[1][tid][4 + c] + elp[2][tid][4 + c] +
                           elp[3][tid][4 + c];
                elr[(size_t)row * 8 + c] = el;
                elr[(size_t)row * 8 + 4 + c] = er;
            }
        }
    }
}

// ---------------- layer-0 aggregate; emits h1 (fp8 e4m3) + el1/er1 (fp32) ------
// fp8-h1 retest, properly isolated: round-17's failure was the W-staging bug
// (round 18 proved it -- identical absmax with fp8 reverted). h1's quantization
// enters the output ONLY linearly through the final global mean; el1/er1 are
// computed from fp32 r BEFORE quantization.

__global__ __launch_bounds__(256) void k_agg0(const unsigned short* __restrict__ z16,
                                              const float4* __restrict__ w4,
                                              const int* __restrict__ rowstart,
                                              const int2* __restrict__ csr_sd,
                                              const float* __restrict__ bias,
                                              const float* __restrict__ wlr1,
                                              unsigned char* __restrict__ h1q,
                                              float* __restrict__ elr1, int N) {
    int node = __builtin_amdgcn_readfirstlane(blockIdx.x * 4 + (threadIdx.x >> 6));
    int lane = threadIdx.x & 63;
    if (node >= N) return;
    float4 wl4 = *(const float4*)(wlr1 + lane * 8);
    float4 wr4 = *(const float4*)(wlr1 + lane * 8 + 4);
    int s = rowstart[node], e = rowstart[node + 1];
    float s0 = 0.f, s1 = 0.f, s2 = 0.f;
    float a0 = 0.f, a1 = 0.f, a2 = 0.f;
    int i = s;
    for (; i + 4 <= e; i += 4) {
        float4 w0 = w4[i];
        float4 w1 = w4[i + 1];
        float4 w2 = w4[i + 2];
        float4 w3 = w4[i + 3];
        int sr0 = csr_sd[i].x;
        int sr1 = csr_sd[i + 1].x;
        int sr2 = csr_sd[i + 2].x;
        int sr3 = csr_sd[i + 3].x;
        const unsigned short* zr0 = z16 + (size_t)sr0 * OUTW;
        const unsigned short* zr1 = z16 + (size_t)sr1 * OUTW;
        const unsigned short* zr2 = z16 + (size_t)sr2 * OUTW;
        const unsigned short* zr3 = z16 + (size_t)sr3 * OUTW;
        unsigned short p00 = zr0[lane], p01 = zr0[HID + lane], p02 = zr0[2 * HID + lane];
        unsigned short p10 = zr1[lane], p11 = zr1[HID + lane], p12 = zr1[2 * HID + lane];
        unsigned short p20 = zr2[lane], p21 = zr2[HID + lane], p22 = zr2[2 * HID + lane];
        unsigned short p30 = zr3[lane], p31 = zr3[HID + lane], p32 = zr3[2 * HID + lane];
        s0 += (w0.x + w1.x) + (w2.x + w3.x);
        s1 += (w0.y + w1.y) + (w2.y + w3.y);
        s2 += (w0.z + w1.z) + (w2.z + w3.z);
        a0 = fmaf(w0.x, bf2f(p00), a0);
        a1 = fmaf(w0.y, bf2f(p01), a1);
        a2 = fmaf(w0.z, bf2f(p02), a2);
        a0 = fmaf(w1.x, bf2f(p10), a0);
        a1 = fmaf(w1.y, bf2f(p11), a1);
        a2 = fmaf(w1.z, bf2f(p12), a2);
        a0 = fmaf(w2.x, bf2f(p20), a0);
        a1 = fmaf(w2.y, bf2f(p21), a1);
        a2 = fmaf(w2.z, bf2f(p22), a2);
        a0 = fmaf(w3.x, bf2f(p30), a0);
        a1 = fmaf(w3.y, bf2f(p31), a1);
        a2 = fmaf(w3.z, bf2f(p32), a2);
    }
    for (; i < e; ++i) {
        float4 wv = w4[i];
        int sr = csr_sd[i].x;
        const unsigned short* zr = z16 + (size_t)sr * OUTW;
        s0 += wv.x; s1 += wv.y; s2 += wv.z;
        a0 = fmaf(wv.x, bf2f(zr[lane]), a0);
        a1 = fmaf(wv.y, bf2f(zr[HID + lane]), a1);
        a2 = fmaf(wv.z, bf2f(zr[2 * HID + lane]), a2);
    }
    float r = bias[lane] + bias[HID + lane] + bias[2 * HID + lane];
    if (s0 > 0.f) r += a0 / s0;
    if (s1 > 0.f) r += a1 / s1;
    if (s2 > 0.f) r += a2 / s2;
    r *= (1.f / 3.f);

    h1q[(size_t)node * HID + lane] = f2q(r);
    float pl0 = r * wl4.x, pl1 = r * wl4.y, pl2 = r * wl4.z;
    float pr0 = r * wr4.x, pr1 = r * wr4.y, pr2 = r * wr4.z;
#pragma unroll
    for (int m = 1; m < 64; m <<= 1) {
        pl0 += __shfl_xor(pl0, m, 64);
        pl1 += __shfl_xor(pl1, m, 64);
        pl2 += __shfl_xor(pl2, m, 64);
        pr0 += __shfl_xor(pr0, m, 64);
        pr1 += __shfl_xor(pr1, m, 64);
        pr2 += __shfl_xor(pr2, m, 64);
    }
    if (lane == 0) {
        elr1[(size_t)node * 8 + 0] = pl0;
        elr1[(size_t)node * 8 + 1] = pl1;
        elr1[(size_t)node * 8 + 2] = pl2;
        elr1[(size_t)node * 8 + 4] = pr0;
        elr1[(size_t)node * 8 + 5] = pr1;
        elr1[(size_t)node * 8 + 6] = pr2;
    }
}

// ---------------- layer-1: dst-grouped grid-stride pass (fp8 h1 gather) --------

__global__ __launch_bounds__(256) void k_lsum(const unsigned char* __restrict__ h1q,
                                              const float4* __restrict__ w4,
                                              const int* __restrict__ rowstart,
                                              const int2* __restrict__ csr_sd,
                                              float* __restrict__ partial, int N) {
    int lane = threadIdx.x & 63;
    int w = threadIdx.x >> 6;
    int wid = __builtin_amdgcn_readfirstlane(blockIdx.x * 4 + (threadIdx.x >> 6));
    int nw = gridDim.x * 4;
    float g0 = 0.f, g1 = 0.f, g2 = 0.f;
    for (int node = wid; node < N; node += nw) {
        int s = rowstart[node], e = rowstart[node + 1];
        if (s == e) continue;
        float s0 = 0.f, s1 = 0.f, s2 = 0.f;
        float a0 = 0.f, a1 = 0.f, a2 = 0.f;
        int i = s;
        for (; i + 4 <= e; i += 4) {
            float4 w0 = w4[i];
            float4 w1 = w4[i + 1];
            float4 w2 = w4[i + 2];
            float4 w3 = w4[i + 3];
            int sr0 = csr_sd[i].x;
            int sr1 = csr_sd[i + 1].x;
            int sr2 = csr_sd[i + 2].x;
            int sr3 = csr_sd[i + 3].x;
            float v0 = q2f(h1q[(size_t)sr0 * HID + lane]);
            float v1 = q2f(h1q[(size_t)sr1 * HID + lane]);
            float v2 = q2f(h1q[(size_t)sr2 * HID + lane]);
            float v3 = q2f(h1q[(size_t)sr3 * HID + lane]);
            s0 += (w0.x + w1.x) + (w2.x + w3.x);
            s1 += (w0.y + w1.y) + (w2.y + w3.y);
            s2 += (w0.z + w1.z) + (w2.z + w3.z);
            a0 = fmaf(w0.x, v0, a0);
            a1 = fmaf(w0.y, v0, a1);
            a2 = fmaf(w0.z, v0, a2);
            a0 = fmaf(w1.x, v1, a0);
            a1 = fmaf(w1.y, v1, a1);
            a2 = fmaf(w1.z, v1, a2);
            a0 = fmaf(w2.x, v2, a0);
            a1 = fmaf(w2.y, v2, a1);
            a2 = fmaf(w2.z, v2, a2);
            a0 = fmaf(w3.x, v3, a0);
            a1 = fmaf(w3.y, v3, a1);
            a2 = fmaf(w3.z, v3, a2);
        }
        for (; i < e; ++i) {
            float4 wv = w4[i];
            int sr = csr_sd[i].x;
            float v = q2f(h1q[(size_t)sr * HID + lane]);
            s0 += wv.x; s1 += wv.y; s2 += wv.z;
            a0 = fmaf(wv.x, v, a0);
            a1 = fmaf(wv.y, v, a1);
            a2 = fmaf(wv.z, v, a2);
        }
        if (s0 > 0.f) g0 += a0 / s0;
        if (s1 > 0.f) g1 += a1 / s1;
        if (s2 > 0.f) g2 += a2 / s2;
    }
    __shared__ float sh[4][3][64];
    sh[w][0][lane] = g0;
    sh[w][1][lane] = g1;
    sh[w][2][lane] = g2;
    __syncthreads();
    if (w == 0) {
        float t0 = sh[0][0][lane] + sh[1][0][lane] + sh[2][0][lane] + sh[3][0][lane];
        float t1 = sh[0][1][lane] + sh[1][1][lane] + sh[2][1][lane] + sh[3][1][lane];
        float t2 = sh[0][2][lane] + sh[1][2][lane] + sh[2][2][lane] + sh[3][2][lane];
        float* p = partial + (size_t)blockIdx.x * OUTW;
        p[0 * HID + lane] = t0;
        p[1 * HID + lane] = t1;
        p[2 * HID + lane] = t2;
    }
}

// ---------------- reduce partials: macc[f] = sum_b partial[b][f] ---------------

__global__ __launch_bounds__(256) void k_red(const float* __restrict__ partial,
                                             float* __restrict__ macc, int nb) {
    int f = blockIdx.x;
    int t = threadIdx.x;
    float s = 0.f;
    for (int b = t; b < nb; b += 256) s += partial[(size_t)b * OUTW + f];
    __shared__ float sh[256];
    sh[t] = s;
    __syncthreads();
    for (int off = 128; off > 0; off >>= 1) {
        if (t < off) sh[t] += sh[t + off];
        __syncthreads();
    }
    if (t == 0) macc[f] = sh[0];
}

// ---------------- final: out[f] = macc @ W1_stacked /(3N) + mean bias ----------

__global__ void k_final(const float* __restrict__ macc, const float* __restrict__ W1,
                        const float* __restrict__ b1, float* __restrict__ out, int N) {
    int f = threadIdx.x;
    if (f >= HID) return;
    float s = 0.f;
#pragma unroll
    for (int hh = 0; hh < HEADS; ++hh)
        for (int k = 0; k < HID; ++k)
            s = fmaf(macc[hh * HID + k], W1[k * OUTW + hh * HID + f], s);
    float bb = b1[f] + b1[HID + f] + b1[2 * HID + f];
    out[f] = s / (3.0f * (float)N) + bb * (1.f / 3.f);
}

// ---------------- launch ----------------

extern "C" void kernel_launch(void* const* d_in, const int* in_sizes, int n_in,
                              void* d_out, int out_size, void* d_ws, size_t ws_size,
                              hipStream_t stream) {
    const float* h   = (const float*)d_in[0];
    const int* src   = (const int*)d_in[1];
    const int* dst   = (const int*)d_in[2];
    const float* W0  = (const float*)d_in[3];
    const float* al0 = (const float*)d_in[4];
    const float* ar0 = (const float*)d_in[5];
    const float* b0  = (const float*)d_in[6];
    const float* W1  = (const float*)d_in[7];
    const float* al1 = (const float*)d_in[8];
    const float* ar1 = (const float*)d_in[9];
    const float* b1  = (const float*)d_in[10];
    float* out = (float*)d_out;

    const int N = in_sizes[0] / NS;
    const int E = in_sizes[1];

    char* ws = (char*)d_ws;
    size_t off = 0;
    auto alloc = [&](size_t bytes) {
        size_t r = off;
        off = (off + bytes + 255) & ~(size_t)255;
        return r;
    };
    unsigned short* z16 = (unsigned short*)(ws + alloc((size_t)N * OUTW * 2));
    unsigned char* h1q  = (unsigned char*)(ws + alloc((size_t)N * HID));
    float* elr0     = (float*)(ws + alloc((size_t)N * 8 * 4));
    float* elr1     = (float*)(ws + alloc((size_t)N * 8 * 4));
    float4* w0arr   = (float4*)(ws + alloc((size_t)E * 16));
    float4* w1arr   = (float4*)(ws + alloc((size_t)E * 16));
    float* partial  = (float*)(ws + alloc((size_t)NB_LSUM * OUTW * 4));
    float* macc     = (float*)(ws + alloc(OUTW * 4));
    int* cnt        = (int*)(ws + alloc((size_t)N * 4));
    int* rowstart   = (int*)(ws + alloc((size_t)(N + 1) * 4));
    int* cursor     = (int*)(ws + alloc((size_t)N * 4));
    int2* csr_sd    = (int2*)(ws + alloc((size_t)E * 8));
    int* blocksums  = (int*)(ws + alloc(4096));
    float* wlr1     = (float*)(ws + alloc(64 * 8 * 4));
    unsigned short* Wtb = (unsigned short*)(ws + alloc((size_t)OUTW * NS * 2));

    const int nbScan = (N + 1023) / 1024;

    // CSR build (by dst) + weight prep
    k_zero_int<<<256, 256, 0, stream>>>(cnt, N);
    k_hist<<<2048, 256, 0, stream>>>(dst, cnt, E);
    k_scan1<<<nbScan, 256, 0, stream>>>(cnt, rowstart, blocksums, N);
    k_scan2<<<1, 64, 0, stream>>>(blocksums, nbScan);
    k_scan3<<<(N + 255) / 256, 256, 0, stream>>>(rowstart, blocksums, cursor, N, E);
    k_scatter<<<2048, 256, 0, stream>>>(src, dst, cursor, csr_sd, E);
    k_prep<<<1, 192, 0, stream>>>(W1, al1, ar1, wlr1);
    k_prepW<<<6, 256, 0, stream>>>(W0, Wtb);

    // layer 0 (MFMA GEMM) -> edge weights -> aggregate
    k_gemm5<<<(N + 63) / 64, 256, 0, stream>>>(h, Wtb, al0, ar0, z16, elr0, N);
    k_w<<<1024, 256, 0, stream>>>(elr0, csr_sd, w0arr, E);
    k_agg0<<<(N + 3) / 4, 256, 0, stream>>>(z16, w0arr, rowstart, csr_sd, b0, wlr1,
                                            h1q, elr1, N);

    // layer 1 (collapsed): edge weights -> grid-stride pass -> reduce -> matvec
    k_w<<<1024, 256, 0, stream>>>(elr1, csr_sd, w1arr, E);
    k_lsum<<<NB_LSUM, 256, 0, stream>>>(h1q, w1arr, rowstart, csr_sd, partial, N);
    k_red<<<OUTW, 256, 0, stream>>>(partial, macc, NB_LSUM);
    k_final<<<1, 64, 0, stream>>>(macc, W1, b1, out, N);
}